// Round 2
// baseline (277.975 us; speedup 1.0000x reference)
//
#include <hip/hip_runtime.h>

// MatrixFactorization via dest-ordered processing.
// out[n] = dot(concat(Wdow[dow[n]],Wtim[tim[n]],Wmon[mon[n]],Wday[day[n]]), Witem[dest[n]])
//
// Round-1 kernel was fetch-path bound: 286 MB L2-miss traffic @3.2 TB/s = 91 us,
// because random dest gathers into the 51.2 MB W_item table thrash the 4 MiB/XCD L2.
// Average row multiplicity = N/100k ~ 10.5. Counting-sort samples by dest so each
// block processes a contiguous dest range -> each W_item row fetched ~once (51 MB
// compulsory instead of ~286 MB).
//
// Pipeline (all on `stream`, graph-capturable):
//   1. zero_hist     : clear 6400-bucket histogram in d_ws
//   2. hist_kernel   : atomicAdd over dest>>4
//   3. scan_kernel   : single-block exclusive scan (6400 = 256 threads x 25)
//   4. scatter_kernel: pos = atomicAdd(offs[b]); payload[pos] = packed(54 bits:
//                      id:20 | dest:17 | dow:3 | time:5 | month:4 | day:5)
//   5. mf_sorted     : half-wave per payload entry, contiguous 512-entry chunk
//                      per block (row reuse stays inside one block / one XCD L2).

constexpr int NDIM = 32;
constexpr int SZ_DOW = 7 * NDIM;     // 224
constexpr int SZ_TIM = 24 * NDIM;    // 768
constexpr int SZ_MON = 12 * NDIM;    // 384
constexpr int SZ_DAY = 31 * NDIM;    // 992
constexpr int B_DOW = 0;
constexpr int B_TIM = B_DOW + SZ_DOW;   // 224
constexpr int B_MON = B_TIM + SZ_TIM;   // 992
constexpr int B_DAY = B_MON + SZ_MON;   // 1376
constexpr int TAB_TOT = B_DAY + SZ_DAY; // 2368 floats = 9472 B LDS

constexpr int NB = 6400;        // buckets; bucket = dest>>4, max 6249
constexpr int SCAN_PER = 25;    // 256 * 25 = 6400

__global__ void zero_hist(int* __restrict__ hist) {
    int i = blockIdx.x * blockDim.x + threadIdx.x;
    if (i < NB) hist[i] = 0;
}

__global__ __launch_bounds__(256) void hist_kernel(const int* __restrict__ dest,
                                                   int* __restrict__ hist, int n) {
    int i = blockIdx.x * blockDim.x + threadIdx.x;
    int stride = gridDim.x * blockDim.x;
    for (; i < n; i += stride) atomicAdd(&hist[dest[i] >> 4], 1);
}

__global__ __launch_bounds__(256) void scan_kernel(const int* __restrict__ hist,
                                                   int* __restrict__ offs) {
    __shared__ int part[256];
    const int t = threadIdx.x;
    int v[SCAN_PER];
    int base = t * SCAN_PER, s = 0;
    for (int i = 0; i < SCAN_PER; i++) { v[i] = hist[base + i]; s += v[i]; }
    part[t] = s;
    __syncthreads();
    if (t == 0) {
        int run = 0;
        for (int j = 0; j < 256; j++) { int x = part[j]; part[j] = run; run += x; }
    }
    __syncthreads();
    int run = part[t];
    for (int i = 0; i < SCAN_PER; i++) { offs[base + i] = run; run += v[i]; }
}

__global__ __launch_bounds__(256) void scatter_kernel(
        const int* __restrict__ dow, const int* __restrict__ tim,
        const int* __restrict__ mon, const int* __restrict__ day,
        const int* __restrict__ dest,
        int* __restrict__ offs, unsigned long long* __restrict__ payload, int n) {
    int i = blockIdx.x * blockDim.x + threadIdx.x;
    int stride = gridDim.x * blockDim.x;
    for (; i < n; i += stride) {
        const int ds = dest[i];
        const int pos = atomicAdd(&offs[ds >> 4], 1);
        unsigned long long p = (unsigned long long)(unsigned)i
            | ((unsigned long long)(unsigned)ds      << 20)
            | ((unsigned long long)(unsigned)dow[i]  << 37)
            | ((unsigned long long)(unsigned)tim[i]  << 40)
            | ((unsigned long long)(unsigned)mon[i]  << 45)
            | ((unsigned long long)(unsigned)day[i]  << 49);
        payload[pos] = p;
    }
}

__global__ __launch_bounds__(256, 8)
void mf_sorted_kernel(const unsigned long long* __restrict__ payload,
                      const float* __restrict__ Wdow, const float* __restrict__ Wtim,
                      const float* __restrict__ Wmon, const float* __restrict__ Wday,
                      const float* __restrict__ Witem,
                      float* __restrict__ out, int n, int chunk)
{
    __shared__ float tab[TAB_TOT];
    const int tid = threadIdx.x;
    for (int i = tid; i < SZ_DOW; i += 256) tab[B_DOW + i] = Wdow[i];
    for (int i = tid; i < SZ_TIM; i += 256) tab[B_TIM + i] = Wtim[i];
    for (int i = tid; i < SZ_MON; i += 256) tab[B_MON + i] = Wmon[i];
    for (int i = tid; i < SZ_DAY; i += 256) tab[B_DAY + i] = Wday[i];
    __syncthreads();

    const int lane = tid & 63;
    const int sub  = lane & 31;
    const int wave = tid >> 6;
    const int half = lane >> 5;
    const int t    = sub >> 3;
    const int dofs = (sub & 7) * 4;
    const int tbase = (t == 0) ? B_DOW : (t == 1) ? B_TIM : (t == 2) ? B_MON : B_DAY;
    const int shf   = (t == 0) ? 37    : (t == 1) ? 40    : (t == 2) ? 45    : 49;
    const int msk   = (t == 0) ? 7     : (t == 1) ? 31    : (t == 2) ? 15    : 31;

    const long base = (long)blockIdx.x * chunk;
    const int lim = (int)min((long)chunk, (long)n - base);

    for (int i = wave * 2 + half; i < lim; i += 8) {
        const unsigned long long p = payload[base + i];
        const int id = (int)(p & 0xFFFFFull);
        const int ds = (int)((p >> 20) & 0x1FFFFull);
        const int iw = (int)((p >> shf) & (unsigned long long)msk);

        const float4 u  = *reinterpret_cast<const float4*>(&tab[tbase + iw * NDIM + dofs]);
        const float4 it = *reinterpret_cast<const float4*>(&Witem[(long)ds * 128 + sub * 4]);

        float r = u.x * it.x + u.y * it.y + u.z * it.z + u.w * it.w;
        r += __shfl_xor(r, 16);
        r += __shfl_xor(r, 8);
        r += __shfl_xor(r, 4);
        r += __shfl_xor(r, 2);
        r += __shfl_xor(r, 1);

        if (sub == 0) out[id] = r;
    }
}

// ---- Round-1 direct kernel kept as fallback (ws too small / n too large) ----
__global__ __launch_bounds__(256, 8)
void mf_dot_kernel(const int* __restrict__ dow, const int* __restrict__ tim,
                   const int* __restrict__ mon, const int* __restrict__ day,
                   const int* __restrict__ dest,
                   const float* __restrict__ Wdow, const float* __restrict__ Wtim,
                   const float* __restrict__ Wmon, const float* __restrict__ Wday,
                   const float* __restrict__ Witem,
                   float* __restrict__ out, int n_samples)
{
    __shared__ float tab[TAB_TOT];
    const int tid = threadIdx.x;
    for (int i = tid; i < SZ_DOW; i += 256) tab[B_DOW + i] = Wdow[i];
    for (int i = tid; i < SZ_TIM; i += 256) tab[B_TIM + i] = Wtim[i];
    for (int i = tid; i < SZ_MON; i += 256) tab[B_MON + i] = Wmon[i];
    for (int i = tid; i < SZ_DAY; i += 256) tab[B_DAY + i] = Wday[i];
    __syncthreads();

    const int lane = tid & 63;
    const int sub  = lane & 31;
    const int wave = tid >> 6;
    const int half = lane >> 5;
    const int t    = sub >> 3;
    const int dofs = (sub & 7) * 4;
    const int* idxp  = (t == 0) ? dow   : (t == 1) ? tim   : (t == 2) ? mon   : day;
    const int  tbase = (t == 0) ? B_DOW : (t == 1) ? B_TIM : (t == 2) ? B_MON : B_DAY;
    long n = (long)blockIdx.x * 8 + wave * 2 + half;
    const long stride = (long)gridDim.x * 8;
    for (; n < n_samples; n += stride) {
        const int idx = idxp[n];
        const int ds  = dest[n];
        const float4 u  = *reinterpret_cast<const float4*>(&tab[tbase + idx * NDIM + dofs]);
        const float4 it = *reinterpret_cast<const float4*>(&Witem[(long)ds * 128 + sub * 4]);
        float r = u.x * it.x + u.y * it.y + u.z * it.z + u.w * it.w;
        r += __shfl_xor(r, 16);
        r += __shfl_xor(r, 8);
        r += __shfl_xor(r, 4);
        r += __shfl_xor(r, 2);
        r += __shfl_xor(r, 1);
        if (sub == 0) out[n] = r;
    }
}

extern "C" void kernel_launch(void* const* d_in, const int* in_sizes, int n_in,
                              void* d_out, int out_size, void* d_ws, size_t ws_size,
                              hipStream_t stream)
{
    const int*   dow   = (const int*)d_in[0];
    const int*   tim   = (const int*)d_in[1];
    const int*   mon   = (const int*)d_in[2];
    const int*   day   = (const int*)d_in[3];
    const int*   dest  = (const int*)d_in[4];
    const float* Wdow  = (const float*)d_in[5];
    const float* Wtim  = (const float*)d_in[6];
    const float* Wmon  = (const float*)d_in[7];
    const float* Wday  = (const float*)d_in[8];
    const float* Witem = (const float*)d_in[9];
    float* out = (float*)d_out;

    const int n = in_sizes[0];  // 1048576

    // ws layout: [hist NB ints][offs NB ints][pad to 64KB][payload n x u64]
    const size_t payload_off = 64 * 1024;
    const size_t need = payload_off + (size_t)n * 8;

    if ((size_t)ws_size < need || n > (1 << 20)) {
        // fallback: direct gather kernel (round-1, 91 us)
        hipLaunchKernelGGL(mf_dot_kernel, dim3(2048), dim3(256), 0, stream,
                           dow, tim, mon, day, dest,
                           Wdow, Wtim, Wmon, Wday, Witem, out, n);
        return;
    }

    int* hist = (int*)d_ws;
    int* offs = hist + NB;
    unsigned long long* payload = (unsigned long long*)((char*)d_ws + payload_off);

    hipLaunchKernelGGL(zero_hist, dim3((NB + 255) / 256), dim3(256), 0, stream, hist);
    hipLaunchKernelGGL(hist_kernel, dim3(1024), dim3(256), 0, stream, dest, hist, n);
    hipLaunchKernelGGL(scan_kernel, dim3(1), dim3(256), 0, stream, hist, offs);
    hipLaunchKernelGGL(scatter_kernel, dim3(1024), dim3(256), 0, stream,
                       dow, tim, mon, day, dest, offs, payload, n);

    const int chunk = 512;
    const int nblk = (n + chunk - 1) / chunk;  // 2048
    hipLaunchKernelGGL(mf_sorted_kernel, dim3(nblk), dim3(256), 0, stream,
                       payload, Wdow, Wtim, Wmon, Wday, Witem, out, n, chunk);
}

// Round 3
// 173.756 us; speedup vs baseline: 1.5998x; 1.5998x over previous
//
#include <hip/hip_runtime.h>

// MatrixFactorization: out[n] = dot(concat(Wdow[dow[n]],Wtim[tim[n]],Wmon[mon[n]],Wday[day[n]]),
//                                   Witem[dest[n]])
//
// Round-1 (32 lanes/sample, 5-shuffle reduce): 91 us @ 3.26 TB/s fabric.
// Round-2 (dest-sorted):                       84 us @ 1.0 TB/s  -> NOT BW-bound.
// Both share a latency-/DS-bound per-sample chain. Round-3 restructures compute:
//   - 8 lanes/sample (lane l8 owns cols l8*4..+4 of each 32-dim slice j=0..3)
//     -> 3-shuffle reduce per 8 samples (DS-swizzle bytes/sample drop 6.7x)
//   - indices pre-packed into one int by a streaming pre-kernel (2 loads/sample)
//   - U=2 samples per lane-group in flight, loads hoisted -> 16 independent
//     item-row fetches outstanding per wave (vs 2) for latency hiding
//
// Item fragment j of lane l8: Witem[dest*128 + j*32 + l8*4 ..+4]
//   -> per 8-lane group, load j touches 128 contiguous bytes (coalesced).
// User fragment j: LDS tab_j[idx_j*32 + l8*4 ..+4] (128 B/row, conflict-free b128).

constexpr int NDIM = 32;
constexpr int SZ_DOW = 7 * NDIM;     // 224
constexpr int SZ_TIM = 24 * NDIM;    // 768
constexpr int SZ_MON = 12 * NDIM;    // 384
constexpr int SZ_DAY = 31 * NDIM;    // 992
constexpr int B_DOW = 0;
constexpr int B_TIM = B_DOW + SZ_DOW;   // 224
constexpr int B_MON = B_TIM + SZ_TIM;   // 992
constexpr int B_DAY = B_MON + SZ_MON;   // 1376
constexpr int TAB_TOT = B_DAY + SZ_DAY; // 2368 floats = 9472 B LDS

__global__ __launch_bounds__(256)
void pack_kernel(const int* __restrict__ dow, const int* __restrict__ tim,
                 const int* __restrict__ mon, const int* __restrict__ day,
                 int* __restrict__ packed, int n) {
    int i = blockIdx.x * blockDim.x + threadIdx.x;
    int stride = gridDim.x * blockDim.x;
    for (; i < n; i += stride)
        packed[i] = dow[i] | (tim[i] << 8) | (mon[i] << 16) | (day[i] << 24);
}

__global__ __launch_bounds__(256, 4)
void mf_mlp_kernel(const int* __restrict__ packed, const int* __restrict__ dest,
                   const float* __restrict__ Wdow, const float* __restrict__ Wtim,
                   const float* __restrict__ Wmon, const float* __restrict__ Wday,
                   const float* __restrict__ Witem,
                   float* __restrict__ out, int n)
{
    __shared__ float tab[TAB_TOT];
    const int tid = threadIdx.x;
    for (int i = tid; i < SZ_DOW; i += 256) tab[B_DOW + i] = Wdow[i];
    for (int i = tid; i < SZ_TIM; i += 256) tab[B_TIM + i] = Wtim[i];
    for (int i = tid; i < SZ_MON; i += 256) tab[B_MON + i] = Wmon[i];
    for (int i = tid; i < SZ_DAY; i += 256) tab[B_DAY + i] = Wday[i];
    __syncthreads();

    const int sub = tid & 63;
    const int wv  = tid >> 6;     // wave in block 0..3
    const int g   = sub >> 3;     // 8-lane group 0..7 (one sample slot each)
    const int col = (sub & 7) * 4;
    const int l8  = sub & 7;
    const int tb[4] = {B_DOW, B_TIM, B_MON, B_DAY};

    const long gw     = (long)blockIdx.x * 4 + wv;
    const long nwaves = (long)gridDim.x * 4;

    for (long base = gw * 16; base < n; base += nwaves * 16) {
        const long n0 = base + g;       // slot u=0: samples base..base+7
        const long n1 = base + 8 + g;   // slot u=1: samples base+8..base+15
        const bool v0 = n0 < n, v1 = n1 < n;

        // --- issue all independent loads up front (MLP) ---
        const int pk0 = v0 ? packed[n0] : 0;
        const int d0  = v0 ? dest[n0]   : 0;
        const int pk1 = v1 ? packed[n1] : 0;
        const int d1  = v1 ? dest[n1]   : 0;

        const float* r0 = Witem + (long)d0 * 128 + col;
        const float* r1 = Witem + (long)d1 * 128 + col;

        float4 it0[4], it1[4], us0[4], us1[4];
#pragma unroll
        for (int j = 0; j < 4; j++) it0[j] = *reinterpret_cast<const float4*>(r0 + j * NDIM);
#pragma unroll
        for (int j = 0; j < 4; j++) it1[j] = *reinterpret_cast<const float4*>(r1 + j * NDIM);
#pragma unroll
        for (int j = 0; j < 4; j++) {
            const int idx = (pk0 >> (8 * j)) & 0xFF;
            us0[j] = *reinterpret_cast<const float4*>(&tab[tb[j] + idx * NDIM + col]);
        }
#pragma unroll
        for (int j = 0; j < 4; j++) {
            const int idx = (pk1 >> (8 * j)) & 0xFF;
            us1[j] = *reinterpret_cast<const float4*>(&tab[tb[j] + idx * NDIM + col]);
        }

        // --- 16-float partial dot per lane ---
        float p0 = 0.f, p1 = 0.f;
#pragma unroll
        for (int j = 0; j < 4; j++) {
            p0 += it0[j].x * us0[j].x + it0[j].y * us0[j].y
                + it0[j].z * us0[j].z + it0[j].w * us0[j].w;
            p1 += it1[j].x * us1[j].x + it1[j].y * us1[j].y
                + it1[j].z * us1[j].z + it1[j].w * us1[j].w;
        }

        // --- 3-level reduce within the 8-lane group (two independent trees) ---
        p0 += __shfl_xor(p0, 1);  p1 += __shfl_xor(p1, 1);
        p0 += __shfl_xor(p0, 2);  p1 += __shfl_xor(p1, 2);
        p0 += __shfl_xor(p0, 4);  p1 += __shfl_xor(p1, 4);

        if (l8 == 0) {
            if (v0) out[n0] = p0;   // 8 consecutive addresses across groups
            if (v1) out[n1] = p1;
        }
    }
}

// ---- Round-1 direct kernel kept as fallback (ws too small for packed[]) ----
__global__ __launch_bounds__(256, 8)
void mf_dot_kernel(const int* __restrict__ dow, const int* __restrict__ tim,
                   const int* __restrict__ mon, const int* __restrict__ day,
                   const int* __restrict__ dest,
                   const float* __restrict__ Wdow, const float* __restrict__ Wtim,
                   const float* __restrict__ Wmon, const float* __restrict__ Wday,
                   const float* __restrict__ Witem,
                   float* __restrict__ out, int n_samples)
{
    __shared__ float tab[TAB_TOT];
    const int tid = threadIdx.x;
    for (int i = tid; i < SZ_DOW; i += 256) tab[B_DOW + i] = Wdow[i];
    for (int i = tid; i < SZ_TIM; i += 256) tab[B_TIM + i] = Wtim[i];
    for (int i = tid; i < SZ_MON; i += 256) tab[B_MON + i] = Wmon[i];
    for (int i = tid; i < SZ_DAY; i += 256) tab[B_DAY + i] = Wday[i];
    __syncthreads();
    const int lane = tid & 63;
    const int sub  = lane & 31;
    const int wave = tid >> 6;
    const int half = lane >> 5;
    const int t    = sub >> 3;
    const int dofs = (sub & 7) * 4;
    const int* idxp  = (t == 0) ? dow   : (t == 1) ? tim   : (t == 2) ? mon   : day;
    const int  tbase = (t == 0) ? B_DOW : (t == 1) ? B_TIM : (t == 2) ? B_MON : B_DAY;
    long n = (long)blockIdx.x * 8 + wave * 2 + half;
    const long stride = (long)gridDim.x * 8;
    for (; n < n_samples; n += stride) {
        const int idx = idxp[n];
        const int ds  = dest[n];
        const float4 u  = *reinterpret_cast<const float4*>(&tab[tbase + idx * NDIM + dofs]);
        const float4 it = *reinterpret_cast<const float4*>(&Witem[(long)ds * 128 + sub * 4]);
        float r = u.x * it.x + u.y * it.y + u.z * it.z + u.w * it.w;
        r += __shfl_xor(r, 16);
        r += __shfl_xor(r, 8);
        r += __shfl_xor(r, 4);
        r += __shfl_xor(r, 2);
        r += __shfl_xor(r, 1);
        if (sub == 0) out[n] = r;
    }
}

extern "C" void kernel_launch(void* const* d_in, const int* in_sizes, int n_in,
                              void* d_out, int out_size, void* d_ws, size_t ws_size,
                              hipStream_t stream)
{
    const int*   dow   = (const int*)d_in[0];
    const int*   tim   = (const int*)d_in[1];
    const int*   mon   = (const int*)d_in[2];
    const int*   day   = (const int*)d_in[3];
    const int*   dest  = (const int*)d_in[4];
    const float* Wdow  = (const float*)d_in[5];
    const float* Wtim  = (const float*)d_in[6];
    const float* Wmon  = (const float*)d_in[7];
    const float* Wday  = (const float*)d_in[8];
    const float* Witem = (const float*)d_in[9];
    float* out = (float*)d_out;

    const int n = in_sizes[0];  // 1048576

    if (ws_size < (size_t)n * sizeof(int)) {
        hipLaunchKernelGGL(mf_dot_kernel, dim3(2048), dim3(256), 0, stream,
                           dow, tim, mon, day, dest,
                           Wdow, Wtim, Wmon, Wday, Witem, out, n);
        return;
    }

    int* packed = (int*)d_ws;
    hipLaunchKernelGGL(pack_kernel, dim3(1024), dim3(256), 0, stream,
                       dow, tim, mon, day, packed, n);
    hipLaunchKernelGGL(mf_mlp_kernel, dim3(2048), dim3(256), 0, stream,
                       packed, dest, Wdow, Wtim, Wmon, Wday, Witem, out, n);
}